// Round 11
// baseline (3323.064 us; speedup 1.0000x reference)
//
#include <hip/hip_runtime.h>
#include <hip/hip_bf16.h>

typedef __attribute__((ext_vector_type(8))) short short8;
typedef __attribute__((ext_vector_type(4))) float f32x4;
typedef unsigned int u32;
typedef unsigned short u16;

#define T_STEPS 512
#define B_SZ    128
#define I_SZ    512
#define U_SZ    1024
#define K_TOT   1536   // 512 x-part + 1024 h-part

// ws layout (bytes)
#define XB_OFF   0            // X as bf16 [B][T][I] = 67,108,864 B
#define WC_OFF   67108864     // W packed [gcol][k] bf16 = 12,582,912 B
#define FLAG_OFF 79691776     // 512 u32: [stream 2][cluster 4][wloc 64]
#define HBUF_OFF 79708160     // [2][128][1024] bf16 = 524,288 B
// total 80,232,448 B

__device__ __forceinline__ u16 f2bf(float f) {
  u32 u = __float_as_uint(f);
  u32 r = (u + 0x7fffu + ((u >> 16) & 1u)) >> 16;   // RNE; inputs finite
  return (u16)r;
}
__device__ __forceinline__ float sigm(float x) { return 1.f / (1.f + __expf(-x)); }
__device__ __forceinline__ float tanh_s(float x) {
  float ax = fabsf(x);
  float e  = __expf(-2.f * ax);
  float t  = (1.f - e) / (1.f + e);
  return copysignf(t, x);
}

// ---- prep kernels ---------------------------------------------------------
__global__ void k_convX(const float* __restrict__ X, u16* __restrict__ Xb) {
  u32 i = blockIdx.x * 256u + threadIdx.x;            // covers 8,388,608 exactly
  float4 v = reinterpret_cast<const float4*>(X)[i];
  uint2 o;
  o.x = (u32)f2bf(v.x) | ((u32)f2bf(v.y) << 16);
  o.y = (u32)f2bf(v.z) | ((u32)f2bf(v.w) << 16);
  reinterpret_cast<uint2*>(Xb)[i] = o;
}

__global__ void k_packW(const float* __restrict__ Wih, const float* __restrict__ Whh,
                        u16* __restrict__ Wc) {
  const int gcol = blockIdx.x;
  for (int k = threadIdx.x; k < K_TOT; k += 256) {
    float v = (k < I_SZ) ? Wih[(size_t)gcol * I_SZ + k]
                         : Whh[(size_t)gcol * U_SZ + (k - I_SZ)];
    Wc[(size_t)gcol * K_TOT + k] = f2bf(v);
  }
}

__global__ void k_zero(u32* __restrict__ hz, u32* __restrict__ flags) {
  u32 i = blockIdx.x * 256u + threadIdx.x;            // 514 blocks = 131,584
  if (i < 131072u)      hz[i] = 0u;                   // both h buffers
  else                  flags[i - 131072u] = 0u;      // 512 flags
}

// ---- communication primitives (R2/R3/R6-proven) ---------------------------
__device__ __forceinline__ short8 ld_h16(const u16* p) {
  short8 r;
  asm volatile("global_load_dwordx4 %0, %1, off sc0 sc1" : "=v"(r) : "v"(p));
  return r;   // NOT ready until s_waitcnt vmcnt(0)
}
__device__ __forceinline__ void st_h(u16* p, u32 v) {
  asm volatile("global_store_short %0, %1, off sc0 sc1" :: "v"(p), "v"(v) : "memory");
}
__device__ __forceinline__ short8 ld_w16(const u16* p) {
  short8 r;
  asm volatile("global_load_dwordx4 %0, %1, off" : "=v"(r) : "v"(p));
  return r;   // NOT ready until s_waitcnt vmcnt(0)
}

// ---- persistent dual-stream scan ------------------------------------------
// 256 WGs x 512 thr, 1 WG/CU. cluster cl = wg>>6 (4 clusters x 32 batch rows).
// Each cluster runs TWO independent 16-row LSTM streams (A: rows 0-15,
// B: rows 16-31), alternated so each stream's publish->poll latency is
// hidden under the other stream's body. wloc = wg&63 -> u0 = wloc*16
// (64 gate-cols = 4 gates x 16 units). Waves: kw = wid (8-way K split).
// Per body per wave: 1 row-tile x 4 col-frags x (2 x-iters + 4 h-iters) = 24 MFMA.
__global__ __launch_bounds__(512, 2)
void lstm_scan(const u16* __restrict__ Xb, const u16* __restrict__ Wc,
               const float* __restrict__ bih, const float* __restrict__ bhh,
               u16* __restrict__ hbuf, u32* __restrict__ flags,
               float* __restrict__ out) {
  __shared__ __align__(16) float gbufA[8][64][20];    // [kw][col][row16+pad] 40 KB
  __shared__ __align__(16) float gbufB[8][64][20];    // 40 KB

  const int tid  = threadIdx.x;
  const int wg   = blockIdx.x;
  const int cl   = wg >> 6;                           // cluster
  const int wloc = wg & 63;
  const int rb   = cl * 32;                           // batch row base
  const int u0   = wloc * 16;                         // unit base
  const int wid  = tid >> 6;
  const int lane = tid & 63;
  const int l15  = lane & 15;
  const int kg   = lane >> 4;
  const int kw   = wid;                               // 8-way K split

  // --- persistent W fragments (straight-line asm issue + wait: proven) ---
  short8 Bf[6][4];                                    // 96 regs
  #pragma unroll
  for (int ct = 0; ct < 4; ++ct) {
    const int gcol = ct * 1024 + u0 + l15;            // gate=ct, unit=u0+l15
    const u16* wrow = Wc + (size_t)gcol * K_TOT;
    #pragma unroll
    for (int i = 0; i < 6; ++i) {
      const int k = (i * 8 + kw) * 32 + kg * 8;
      Bf[i][ct] = ld_w16(wrow + k);
    }
  }
  asm volatile("s_waitcnt vmcnt(0)" ::: "memory");
  __builtin_amdgcn_sched_barrier(0);

  // --- cell ownership: thread -> (row4 = tid>>4 in 0..31, unit u0 + (tid&15))
  //     waves 0-3 own stream A (row4 < 16), waves 4-7 stream B. Wave-uniform.
  const int row4 = tid >> 4;                          // 0..31 (global cluster row)
  const int uu   = tid & 15;
  const int ug   = u0 + uu;
  const int r16  = row4 & 15;                         // row within stream
  const int myStream = row4 >> 4;                     // 0 = A, 1 = B
  float bsum[4];
  #pragma unroll
  for (int g = 0; g < 4; ++g) bsum[g] = bih[g * 1024 + ug] + bhh[g * 1024 + ug];
  float c_state = 0.f;
  float* orow = out + (size_t)(rb + row4) * (T_STEPS * U_SZ) + ug;
  const int hidx = (rb + row4) * U_SZ + ug;

  // --- per-stream A-operand bases (1 row-tile each) ---
  const u16* xrowA = Xb + (size_t)(rb + l15)      * (T_STEPS * I_SZ);
  const u16* xrowB = Xb + (size_t)(rb + 16 + l15) * (T_STEPS * I_SZ);
  int hoffA[4], hoffB[4];
  #pragma unroll
  for (int ih = 0; ih < 4; ++ih) {
    const int ku = ((2 + ih) * 8 + kw) * 32 + kg * 8 - 512;   // 0..1023
    hoffA[ih] = (rb + l15) * U_SZ + ku;
    hoffB[ih] = (rb + 16 + l15) * U_SZ + ku;
  }

  // --- flags: [stream][cl][wloc]; poll all 64 cluster flags (lane -> wloc) ---
  u32* flA_my = flags +       (cl << 6) + wloc;
  u32* flB_my = flags + 256 + (cl << 6) + wloc;
  const u32* flA_po = flags +       (cl << 6) + lane;
  const u32* flB_po = flags + 256 + (cl << 6) + lane;

  // ---- one stream body (R6-proven step structure on 16 rows) ----
  auto body = [&](int t, const u16* xrowS, const int* hoffS,
                  const u32* flag_poll, u32* flag_my,
                  float (*gbufS)[64][20], int sId) {
    // poll: all 64 producer WGs of this cluster published stream-S step t-1
    for (;;) {
      const u32 v = __hip_atomic_load(flag_poll, __ATOMIC_RELAXED, __HIP_MEMORY_SCOPE_AGENT);
      if (__all((int)(v >= (u32)t))) break;
      __builtin_amdgcn_s_sleep(1);
    }
    const u16* hsrc = hbuf + ((t & 1) ^ 1) * (B_SZ * U_SZ);
    u16*       hdst = hbuf + (t & 1) * (B_SZ * U_SZ);

    // issue the 4 h-loads (L3), then fill the shadow with the x-phase
    short8 hA[4];
    #pragma unroll
    for (int ih = 0; ih < 4; ++ih) hA[ih] = ld_h16(hsrc + hoffS[ih]);

    f32x4 acc[4];
    #pragma unroll
    for (int ct = 0; ct < 4; ++ct) acc[ct] = (f32x4){0.f, 0.f, 0.f, 0.f};
    const u16* px = xrowS + (size_t)t * I_SZ;
    #pragma unroll
    for (int i = 0; i < 2; ++i) {
      const int k = (i * 8 + kw) * 32 + kg * 8;       // < 512
      const short8 a = *reinterpret_cast<const short8*>(px + k);
      #pragma unroll
      for (int ct = 0; ct < 4; ++ct)
        acc[ct] = __builtin_amdgcn_mfma_f32_16x16x32_bf16(a, Bf[i][ct], acc[ct], 0, 0, 0);
    }

    asm volatile("s_waitcnt vmcnt(0)" ::: "memory");
    __builtin_amdgcn_sched_barrier(0);
    #pragma unroll
    for (int ih = 0; ih < 4; ++ih)
      #pragma unroll
      for (int ct = 0; ct < 4; ++ct)
        acc[ct] = __builtin_amdgcn_mfma_f32_16x16x32_bf16(hA[ih], Bf[2 + ih][ct], acc[ct], 0, 0, 0);

    // partials -> LDS. C/D: col=lane&15, row=(lane>>4)*4+j
    #pragma unroll
    for (int ct = 0; ct < 4; ++ct)
      *reinterpret_cast<float4*>(&gbufS[kw][ct * 16 + l15][kg * 4]) =
          *reinterpret_cast<float4*>(&acc[ct]);
    __syncthreads();                                  // gbufS ready

    // cell update: only this stream's waves (wave-uniform guard)
    if (myStream == sId) {
      float gs[4];
      #pragma unroll
      for (int g = 0; g < 4; ++g) {
        float s = bsum[g];
        #pragma unroll
        for (int k2 = 0; k2 < 8; ++k2) s += gbufS[k2][g * 16 + uu][r16];
        gs[g] = s;
      }
      const float ig = sigm(gs[0]);
      const float fg = sigm(gs[1]);
      const float gg = tanh_s(gs[2]);
      const float og = sigm(gs[3]);
      c_state = fg * c_state + ig * gg;
      const float h = og * tanh_s(c_state);
      st_h(hdst + hidx, (u32)f2bf(h));                // bf16 h -> L3
      orow[(size_t)t * U_SZ] = h;                     // fp32 out
    }

    // drain own stores, join, publish (R6-proven ordering)
    asm volatile("s_waitcnt vmcnt(0)" ::: "memory");
    __syncthreads();                                  // all stores drained; WAR for gbufS
    if (tid == 0)
      __hip_atomic_store(flag_my, (u32)(t + 1), __ATOMIC_RELAXED, __HIP_MEMORY_SCOPE_AGENT);
  };

  for (int t = 0; t < T_STEPS; ++t) {
    body(t, xrowA, hoffA, flA_po, flA_my, gbufA, 0);  // stream A
    body(t, xrowB, hoffB, flB_po, flB_my, gbufB, 1);  // stream B
  }
}

// ---- launch ---------------------------------------------------------------
extern "C" void kernel_launch(void* const* d_in, const int* in_sizes, int n_in,
                              void* d_out, int out_size, void* d_ws, size_t ws_size,
                              hipStream_t stream) {
  const float* X   = (const float*)d_in[0];
  const float* Wih = (const float*)d_in[1];
  const float* Whh = (const float*)d_in[2];
  const float* bih = (const float*)d_in[3];
  const float* bhh = (const float*)d_in[4];
  float* out = (float*)d_out;
  char*  ws  = (char*)d_ws;

  u16* Xb    = (u16*)(ws + XB_OFF);
  u16* Wc    = (u16*)(ws + WC_OFF);
  u32* flags = (u32*)(ws + FLAG_OFF);
  u16* hbuf  = (u16*)(ws + HBUF_OFF);

  hipLaunchKernelGGL(k_convX, dim3(32768), dim3(256), 0, stream, X, Xb);
  hipLaunchKernelGGL(k_packW, dim3(4096), dim3(256), 0, stream, Wih, Whh, Wc);
  hipLaunchKernelGGL(k_zero,  dim3(514),  dim3(256), 0, stream, (u32*)hbuf, flags);

  void* args[] = {(void*)&Xb, (void*)&Wc, (void*)&bih, (void*)&bhh,
                  (void*)&hbuf, (void*)&flags, (void*)&out};
  hipLaunchCooperativeKernel((void*)lstm_scan, dim3(256), dim3(512), args, 0, stream);
}